// Round 1
// 408.853 us; speedup vs baseline: 1.0896x; 1.0896x over previous
//
#include <hip/hip_runtime.h>
#include <hip/hip_bf16.h>
#include <hip/hip_fp16.h>

// MLPSCM round 10: register-resident vals + 2 waves/SIMD.
// R9 was latency-bound at 1 wave/SIMD (Occupancy 11.5%, MfmaUtil 2.7%,
// VALUBusy 14%) — 39KB LDS capped residency. Changes:
//  - vals[64][256] fp16 moved from LDS into MFMA A-fragment registers
//    vf[4][8] (128 VGPRs/lane); chunk loop fully unrolled via template<int K>
//    so every vf index is compile-time (no scratch).
//  - LDS 39.4KB -> ~9KB (Zbuf + 3KB scatter staging + xpos);
//    __launch_bounds__(64,2) forces <=256 VGPR -> 8 blocks/CU (2 waves/SIMD).
//  - single-wave blocks: __syncthreads -> wave_barrier (no vmcnt drains;
//    LDS is in-order within a wave).
//  - serial tail: Zbuf reads hoisted, tanh/sigmoid via v_exp_f32+v_rcp_f32,
//    act_id read from global (wave-uniform -> s_load), acts LDS removed.

typedef _Float16 half8 __attribute__((ext_vector_type(8)));
typedef float    f32x4 __attribute__((ext_vector_type(4)));

constexpr int S_LEN    = 131072;
constexpr int N_NODES  = 256;
constexpr int N_CAUSES = 16;
constexpr int N_COMP   = 240;
constexpr int N_FEAT   = 100;
constexpr float NOISE  = 0.01f;
constexpr float VSC    = 0.0625f;   // vals store scale 1/16
constexpr float VSCI   = 16.0f;

// K_eff per chunk (K=16k+16 rounded up to 32) and hi/lo-plane pack offsets
constexpr int KE_tab[16]  = {0,32,64,64,96,96,128,128,160,160,192,192,224,224,256,256};
constexpr int OFF_tab[16] = {0,0,1024,3072,5120,8192,11264,15360,19456,24576,29696,
                             35840,41984,49152,56320,64512};

__constant__ int c_KE[16]  = {0,32,64,64,96,96,128,128,160,160,192,192,224,224,256,256};
__constant__ int c_OFF[16] = {0,0,1024,3072,5120,8192,11264,15360,19456,24576,29696,
                              35840,41984,49152,56320,64512};

__device__ _Float16 g_WT[72704];      // per chunk: [hi|lo] planes of [16 cols][KE] W^T
__device__ float    g_Wtri[15 * 256]; // per chunk: [l][i] in-chunk triangular W (fp32)

// ---------- content sniffers ----------
__device__ __forceinline__ bool sniff_binary64(const void* p) {
    const unsigned* u = (const unsigned*)p;
    bool ok = true;
    for (int i = 0; i < 64; ++i) ok = ok && (u[i] <= 1u);
    return ok;
}
__device__ __forceinline__ bool sniff_is_bf16(const void* p) {
    const unsigned* u = (const unsigned*)p;
    bool ok = true;
    for (int i = 0; i < 16; ++i) {
        unsigned e = ((u[i] << 16) >> 23) & 0xffu;
        ok = ok && (e >= 100u) && (e <= 132u);
    }
    return ok;
}
__device__ __forceinline__ float bflo(unsigned u) { return __uint_as_float(u << 16); }
__device__ __forceinline__ float bfhi(unsigned u) { return __uint_as_float(u & 0xffff0000u); }

__device__ __forceinline__ void load16(const void* base, long long off, bool isbf, float* o) {
    if (isbf) {
        const uint4* p = (const uint4*)((const unsigned short*)base + off);
        uint4 a = p[0], b = p[1];
        o[0]=bflo(a.x); o[1]=bfhi(a.x); o[2]=bflo(a.y); o[3]=bfhi(a.y);
        o[4]=bflo(a.z); o[5]=bfhi(a.z); o[6]=bflo(a.w); o[7]=bfhi(a.w);
        o[8]=bflo(b.x); o[9]=bfhi(b.x); o[10]=bflo(b.y); o[11]=bfhi(b.y);
        o[12]=bflo(b.z); o[13]=bfhi(b.z); o[14]=bflo(b.w); o[15]=bfhi(b.w);
    } else {
        const float4* p = (const float4*)((const float*)base + off);
        float4 x0=p[0], x1=p[1], x2=p[2], x3=p[3];
        o[0]=x0.x; o[1]=x0.y; o[2]=x0.z; o[3]=x0.w;
        o[4]=x1.x; o[5]=x1.y; o[6]=x1.z; o[7]=x1.w;
        o[8]=x2.x; o[9]=x2.y; o[10]=x2.z; o[11]=x2.w;
        o[12]=x3.x; o[13]=x3.y; o[14]=x3.z; o[15]=x3.w;
    }
}

// ---------- fast activations (raw HW transcendentals; err ~1e-7 rel,
// far below the 5e-4 fp16 vals-quantization already present) ----------
__device__ __forceinline__ float hw_exp2(float x) {
    float r; asm("v_exp_f32 %0, %1" : "=v"(r) : "v"(x)); return r;
}
__device__ __forceinline__ float hw_rcp(float x) {
    float r; asm("v_rcp_f32 %0, %1" : "=v"(r) : "v"(x)); return r;
}
__device__ __forceinline__ float fast_tanh(float x) {
    // tanh(x) = 1 - 2/(exp2(2*log2e*x)+1); inf/0 endpoints saturate correctly
    float t = hw_exp2(x * 2.88539008177792681f);
    return 1.0f - 2.0f * hw_rcp(t + 1.0f);
}
__device__ __forceinline__ float fast_sigmoid(float x) {
    return hw_rcp(1.0f + hw_exp2(x * -1.44269504088896341f));
}

// ---------- prep: pack W^T hi/lo fp16 per chunk + fp32 triangular ----------
__global__ void prep_kernel(const void* __restrict__ A, const void* __restrict__ B) {
    __shared__ int s_mA, s_wbf;
    if (threadIdx.x == 0) {
        s_mA  = sniff_binary64(A) ? 1 : 0;
        s_wbf = sniff_is_bf16(s_mA ? B : A) ? 1 : 0;
    }
    __syncthreads();
    const int*  maskp = (const int*)(s_mA ? A : B);
    const void* Wp    = s_mA ? B : A;
    const int k = blockIdx.x + 1, j0 = 16 * k, KE = c_KE[k], OFF = c_OFF[k];
    const int tid = threadIdx.x;

    for (int n = 0; n < 16; ++n) {
        const int j = j0 + n;
        for (int kk = tid; kk < KE; kk += 256) {
            const int gi = kk * N_NODES + j;
            float w = 0.0f;
            if (maskp[gi])
                w = s_wbf ? __bfloat162float(((const __hip_bfloat16*)Wp)[gi])
                          : ((const float*)Wp)[gi];
            const _Float16 hi = (_Float16)w;
            const _Float16 lo = (_Float16)(w - (float)hi);
            g_WT[OFF + n * KE + kk]           = hi;
            g_WT[OFF + 16 * KE + n * KE + kk] = lo;
        }
    }
    {   // triangular in-chunk weights, fp32
        const int l = tid >> 4, i = tid & 15;
        const int gi = (j0 + l) * N_NODES + (j0 + i);
        float w = 0.0f;
        if (l < i && maskp[gi])
            w = s_wbf ? __bfloat162float(((const __hip_bfloat16*)Wp)[gi])
                      : ((const float*)Wp)[gi];
        g_Wtri[(k - 1) * 256 + tid] = w;
    }
}

#define MFMA16(a, b, c) __builtin_amdgcn_mfma_f32_16x16x32_f16((a), (b), (c), 0, 0, 0)

// One 16-node chunk, everything compile-time-indexed.
// vf[q][t]: lane holds A[q*16 + (lane&15)][32t + (lane>>4)*8 .. +8] (fp16, *VSC)
template<int K>
__device__ __forceinline__ void do_chunk(
    const int lane, const long long sg,
    const void* __restrict__ eps, const bool ebf,
    half8 (&vf)[4][8],
    float* __restrict__ Zbuf, _Float16* __restrict__ stag,
    const short* __restrict__ xpos, const int* __restrict__ act_id,
    float* __restrict__ outX, float* __restrict__ outY, const int yi)
{
    constexpr int j0  = 16 * K;
    constexpr int KE  = KE_tab[K];
    constexpr int NST = KE / 32;
    constexpr int OFF = OFF_tab[K];

    const int mrow = lane & 15;
    const int quad = lane >> 4;

    // eps for this chunk (used only in the tail -> latency hidden under MFMAs)
    float ev[16];
    load16(eps, sg * (long long)N_COMP + (j0 - N_CAUSES), ebf, ev);

    const _Float16* __restrict__ bp = g_WT + OFF + mrow * KE + (quad << 3);

    f32x4 acc0 = {0.f,0.f,0.f,0.f}, acc1 = {0.f,0.f,0.f,0.f};
    f32x4 acc2 = {0.f,0.f,0.f,0.f}, acc3 = {0.f,0.f,0.f,0.f};

    #pragma unroll
    for (int t = 0; t < NST; ++t) {
        const half8 bh = *(const half8*)(bp + (t << 5));
        const half8 bl = *(const half8*)(bp + 16 * KE + (t << 5));
        acc0 = MFMA16(vf[0][t], bh, acc0);
        acc1 = MFMA16(vf[1][t], bh, acc1);
        acc2 = MFMA16(vf[2][t], bh, acc2);
        acc3 = MFMA16(vf[3][t], bh, acc3);
        acc0 = MFMA16(vf[0][t], bl, acc0);
        acc1 = MFMA16(vf[1][t], bl, acc1);
        acc2 = MFMA16(vf[2][t], bl, acc2);
        acc3 = MFMA16(vf[3][t], bl, acc3);
    }

    // C-layout (col=lane&15 = node, row=quad*4+reg = sample) -> Zbuf, unscaled
    {
        const int r0 = quad << 2;
        #pragma unroll
        for (int r = 0; r < 4; ++r) {
            Zbuf[(r0 + r)      * 21 + mrow] = acc0[r] * VSCI;
            Zbuf[(16 + r0 + r) * 21 + mrow] = acc1[r] * VSCI;
            Zbuf[(32 + r0 + r) * 21 + mrow] = acc2[r] * VSCI;
            Zbuf[(48 + r0 + r) * 21 + mrow] = acc3[r] * VSCI;
        }
    }
    __builtin_amdgcn_wave_barrier();   // single-wave block: LDS in-order, no s_barrier needed

    // serial intra-chunk tail: sample = lane (fp32)
    float zz[16];
    #pragma unroll
    for (int i = 0; i < 16; ++i) zz[i] = Zbuf[lane * 21 + i];

    const float* __restrict__ tri = g_Wtri + (K - 1) * 256;
    float vn[16];
    half8 h0, h1;
    #pragma unroll
    for (int i = 0; i < 16; ++i) {
        float z = zz[i] + NOISE * ev[i];
        #pragma unroll
        for (int l = 0; l < i; ++l) z += tri[(l << 4) + i] * vn[l];
        const int a = act_id[j0 - N_CAUSES + i];   // wave-uniform -> s_load
        if (a == 1)      z = fast_tanh(z);
        else if (a == 2) z = fmaxf(z, 0.0f);
        else if (a == 3) z = fast_sigmoid(z);
        vn[i] = z;
        if (i < 8) h0[i] = (_Float16)(z * VSC);
        else       h1[i - 8] = (_Float16)(z * VSC);
        const int xp = xpos[j0 - N_CAUSES + i];    // wave-uniform value (LDS broadcast)
        if (xp >= 0) outX[xp] = z;
        if (j0 + i == yi) outY[sg] = z;
    }

    // scatter new 16 node-values into the A-fragment register layout via staging
    *(half8*)(stag + lane * 24)     = h0;
    *(half8*)(stag + lane * 24 + 8) = h1;
    __builtin_amdgcn_wave_barrier();

    constexpr int TT = K >> 1;          // k-window of nodes j0..j0+15
    constexpr int HB = (K & 1) << 1;    // first owning lane-quad (j0%32)/8
    const int hq = lane >> 4;
    if (hq == HB || hq == HB + 1) {
        const int boff = (hq - HB) << 3;
        #pragma unroll
        for (int q = 0; q < 4; ++q)
            vf[q][TT] = *(const half8*)(stag + (q * 16 + (lane & 15)) * 24 + boff);
    }
    __builtin_amdgcn_wave_barrier();
}

__global__ __launch_bounds__(64, 2)
void scm_kernel(const void* __restrict__ causes,
                const void* __restrict__ eps,
                const int* __restrict__ act_id,
                const void* __restrict__ xidx_raw,
                const int* __restrict__ yidx_raw,
                float* __restrict__ out,
                long long ybase) {
    __shared__ __align__(16) float    Zbuf[64 * 21];   // 5376 B
    __shared__ __align__(16) _Float16 stag[64 * 24];   // 3072 B, 48B/row (16B-aligned slots)
    __shared__ short xpos[N_COMP];                     // 480 B

    const int lane = threadIdx.x;
    const long long sg = (long long)blockIdx.x * 64 + lane;

    for (int t = lane; t < N_COMP; t += 64) xpos[t] = -1;
    const unsigned long long* x64 = (const unsigned long long*)xidx_raw;
    const int*                x32 = (const int*)xidx_raw;
    const bool is64 = ((x64[0] >> 32) == 0ull);
    __builtin_amdgcn_wave_barrier();
    for (int f = lane; f < N_FEAT; f += 64) {
        const int ix = is64 ? (int)x64[f] : x32[f];
        xpos[ix - N_CAUSES] = (short)f;
    }
    __builtin_amdgcn_wave_barrier();
    const int yi  = yidx_raw[0];
    const bool cbf = sniff_is_bf16(causes);
    const bool ebf = sniff_is_bf16(eps);

    // vals in registers: vf[q][t], zero-initialized
    half8 vz;
    #pragma unroll
    for (int e = 0; e < 8; ++e) vz[e] = (_Float16)0.0f;
    half8 vf[4][8];
    #pragma unroll
    for (int q = 0; q < 4; ++q) {
        #pragma unroll
        for (int t = 0; t < 8; ++t) vf[q][t] = vz;
    }

    // causes (nodes 0..15) -> window 0, quads 0/1, via staging scatter
    {
        float cv[16];
        load16(causes, sg * (long long)N_CAUSES, cbf, cv);
        half8 c0, c1;
        #pragma unroll
        for (int i = 0; i < 8; ++i) {
            c0[i] = (_Float16)(cv[i] * VSC);
            c1[i] = (_Float16)(cv[8 + i] * VSC);
        }
        *(half8*)(stag + lane * 24)     = c0;
        *(half8*)(stag + lane * 24 + 8) = c1;
        __builtin_amdgcn_wave_barrier();
        const int hq = lane >> 4;
        if (hq < 2) {
            #pragma unroll
            for (int q = 0; q < 4; ++q)
                vf[q][0] = *(const half8*)(stag + (q * 16 + (lane & 15)) * 24 + (hq << 3));
        }
        __builtin_amdgcn_wave_barrier();
    }

    float* outX = out + sg * N_FEAT;
    float* outY = out + ybase;

    do_chunk< 1>(lane, sg, eps, ebf, vf, Zbuf, stag, xpos, act_id, outX, outY, yi);
    do_chunk< 2>(lane, sg, eps, ebf, vf, Zbuf, stag, xpos, act_id, outX, outY, yi);
    do_chunk< 3>(lane, sg, eps, ebf, vf, Zbuf, stag, xpos, act_id, outX, outY, yi);
    do_chunk< 4>(lane, sg, eps, ebf, vf, Zbuf, stag, xpos, act_id, outX, outY, yi);
    do_chunk< 5>(lane, sg, eps, ebf, vf, Zbuf, stag, xpos, act_id, outX, outY, yi);
    do_chunk< 6>(lane, sg, eps, ebf, vf, Zbuf, stag, xpos, act_id, outX, outY, yi);
    do_chunk< 7>(lane, sg, eps, ebf, vf, Zbuf, stag, xpos, act_id, outX, outY, yi);
    do_chunk< 8>(lane, sg, eps, ebf, vf, Zbuf, stag, xpos, act_id, outX, outY, yi);
    do_chunk< 9>(lane, sg, eps, ebf, vf, Zbuf, stag, xpos, act_id, outX, outY, yi);
    do_chunk<10>(lane, sg, eps, ebf, vf, Zbuf, stag, xpos, act_id, outX, outY, yi);
    do_chunk<11>(lane, sg, eps, ebf, vf, Zbuf, stag, xpos, act_id, outX, outY, yi);
    do_chunk<12>(lane, sg, eps, ebf, vf, Zbuf, stag, xpos, act_id, outX, outY, yi);
    do_chunk<13>(lane, sg, eps, ebf, vf, Zbuf, stag, xpos, act_id, outX, outY, yi);
    do_chunk<14>(lane, sg, eps, ebf, vf, Zbuf, stag, xpos, act_id, outX, outY, yi);
    do_chunk<15>(lane, sg, eps, ebf, vf, Zbuf, stag, xpos, act_id, outX, outY, yi);
}

extern "C" void kernel_launch(void* const* d_in, const int* in_sizes, int n_in,
                              void* d_out, int out_size, void* d_ws, size_t ws_size,
                              hipStream_t stream) {
    // resolve inputs by element count (permutation-proof); fall back to dict order
    int ic = 0, iw = 1, ie = 2, im = 3, ia = 4, ix = 5, iy = 6;
    int c = -1, e = -1, a = -1, x = -1, y = -1, m1 = -1, m2 = -1;
    for (int i = 0; i < n_in; ++i) {
        switch (in_sizes[i]) {
            case S_LEN * N_CAUSES:   c = i; break;
            case S_LEN * N_COMP:     e = i; break;
            case N_COMP:             a = i; break;
            case N_FEAT:             x = i; break;
            case 1:                  y = i; break;
            case N_NODES * N_NODES:  (m1 < 0 ? m1 : m2) = i; break;
        }
    }
    if (c >= 0 && e >= 0 && a >= 0 && x >= 0 && y >= 0 && m1 >= 0 && m2 >= 0) {
        ic = c; ie = e; ia = a; ix = x; iy = y; iw = m1; im = m2;
    }

    const void* causes = d_in[ic];
    const void* TA     = d_in[iw];   // one of {W, mask} — device disambiguates
    const void* TB     = d_in[im];
    const void* eps    = d_in[ie];
    const int*  act_id = (const int*)d_in[ia];
    const void* xidx   = d_in[ix];
    const int*  yidx   = (const int*)d_in[iy];
    float*      out    = (float*)d_out;
    const long long ybase = (long long)out_size - S_LEN;

    prep_kernel<<<15, 256, 0, stream>>>(TA, TB);
    scm_kernel<<<S_LEN / 64, 64, 0, stream>>>(causes, eps, act_id, xidx, yidx, out, ybase);
}

// Round 2
// 356.000 us; speedup vs baseline: 1.2513x; 1.1485x over previous
//
#include <hip/hip_runtime.h>
#include <hip/hip_bf16.h>
#include <hip/hip_fp16.h>

// MLPSCM round 11: coalesced X-writes via feature-major workspace + transpose.
// R10 counters: occupancy 23.8% (grid-limited, 8 waves/CU), MfmaUtil 3.1%,
// WRITE_SIZE 335MB vs 53MB ideal (6.4x write amplification from 400B-stride
// scattered 4B stores; ~13M L2 write txns device-wide). Changes:
//  - tail X-store -> ws[xp*S + sg] (xp wave-uniform, sg lane-linear: perfect
//    256B coalesced full-line stores, no RFO, no partial-line L2 thrash)
//  - new xpose_kernel: [100][S] -> [S][100] LDS-tiled transpose, coalesced
//    reads (ws rows) and dwordx4 writes (out block-span is contiguous 25.6KB)
//  - falls back to direct scattered stores if ws_size too small
//  - everything else identical to R10 (register-resident vals, wave_barrier,
//    fast activations, 2 waves/SIMD)

typedef _Float16 half8 __attribute__((ext_vector_type(8)));
typedef float    f32x4 __attribute__((ext_vector_type(4)));

constexpr int S_LEN    = 131072;
constexpr int N_NODES  = 256;
constexpr int N_CAUSES = 16;
constexpr int N_COMP   = 240;
constexpr int N_FEAT   = 100;
constexpr float NOISE  = 0.01f;
constexpr float VSC    = 0.0625f;   // vals store scale 1/16
constexpr float VSCI   = 16.0f;

// K_eff per chunk (K=16k+16 rounded up to 32) and hi/lo-plane pack offsets
constexpr int KE_tab[16]  = {0,32,64,64,96,96,128,128,160,160,192,192,224,224,256,256};
constexpr int OFF_tab[16] = {0,0,1024,3072,5120,8192,11264,15360,19456,24576,29696,
                             35840,41984,49152,56320,64512};

__constant__ int c_KE[16]  = {0,32,64,64,96,96,128,128,160,160,192,192,224,224,256,256};
__constant__ int c_OFF[16] = {0,0,1024,3072,5120,8192,11264,15360,19456,24576,29696,
                              35840,41984,49152,56320,64512};

__device__ _Float16 g_WT[72704];      // per chunk: [hi|lo] planes of [16 cols][KE] W^T
__device__ float    g_Wtri[15 * 256]; // per chunk: [l][i] in-chunk triangular W (fp32)

// ---------- content sniffers ----------
__device__ __forceinline__ bool sniff_binary64(const void* p) {
    const unsigned* u = (const unsigned*)p;
    bool ok = true;
    for (int i = 0; i < 64; ++i) ok = ok && (u[i] <= 1u);
    return ok;
}
__device__ __forceinline__ bool sniff_is_bf16(const void* p) {
    const unsigned* u = (const unsigned*)p;
    bool ok = true;
    for (int i = 0; i < 16; ++i) {
        unsigned e = ((u[i] << 16) >> 23) & 0xffu;
        ok = ok && (e >= 100u) && (e <= 132u);
    }
    return ok;
}
__device__ __forceinline__ float bflo(unsigned u) { return __uint_as_float(u << 16); }
__device__ __forceinline__ float bfhi(unsigned u) { return __uint_as_float(u & 0xffff0000u); }

__device__ __forceinline__ void load16(const void* base, long long off, bool isbf, float* o) {
    if (isbf) {
        const uint4* p = (const uint4*)((const unsigned short*)base + off);
        uint4 a = p[0], b = p[1];
        o[0]=bflo(a.x); o[1]=bfhi(a.x); o[2]=bflo(a.y); o[3]=bfhi(a.y);
        o[4]=bflo(a.z); o[5]=bfhi(a.z); o[6]=bflo(a.w); o[7]=bfhi(a.w);
        o[8]=bflo(b.x); o[9]=bfhi(b.x); o[10]=bflo(b.y); o[11]=bfhi(b.y);
        o[12]=bflo(b.z); o[13]=bfhi(b.z); o[14]=bflo(b.w); o[15]=bfhi(b.w);
    } else {
        const float4* p = (const float4*)((const float*)base + off);
        float4 x0=p[0], x1=p[1], x2=p[2], x3=p[3];
        o[0]=x0.x; o[1]=x0.y; o[2]=x0.z; o[3]=x0.w;
        o[4]=x1.x; o[5]=x1.y; o[6]=x1.z; o[7]=x1.w;
        o[8]=x2.x; o[9]=x2.y; o[10]=x2.z; o[11]=x2.w;
        o[12]=x3.x; o[13]=x3.y; o[14]=x3.z; o[15]=x3.w;
    }
}

// ---------- fast activations (raw HW transcendentals; err ~1e-7 rel) ----------
__device__ __forceinline__ float hw_exp2(float x) {
    float r; asm("v_exp_f32 %0, %1" : "=v"(r) : "v"(x)); return r;
}
__device__ __forceinline__ float hw_rcp(float x) {
    float r; asm("v_rcp_f32 %0, %1" : "=v"(r) : "v"(x)); return r;
}
__device__ __forceinline__ float fast_tanh(float x) {
    float t = hw_exp2(x * 2.88539008177792681f);
    return 1.0f - 2.0f * hw_rcp(t + 1.0f);
}
__device__ __forceinline__ float fast_sigmoid(float x) {
    return hw_rcp(1.0f + hw_exp2(x * -1.44269504088896341f));
}

// ---------- prep: pack W^T hi/lo fp16 per chunk + fp32 triangular ----------
__global__ void prep_kernel(const void* __restrict__ A, const void* __restrict__ B) {
    __shared__ int s_mA, s_wbf;
    if (threadIdx.x == 0) {
        s_mA  = sniff_binary64(A) ? 1 : 0;
        s_wbf = sniff_is_bf16(s_mA ? B : A) ? 1 : 0;
    }
    __syncthreads();
    const int*  maskp = (const int*)(s_mA ? A : B);
    const void* Wp    = s_mA ? B : A;
    const int k = blockIdx.x + 1, j0 = 16 * k, KE = c_KE[k], OFF = c_OFF[k];
    const int tid = threadIdx.x;

    for (int n = 0; n < 16; ++n) {
        const int j = j0 + n;
        for (int kk = tid; kk < KE; kk += 256) {
            const int gi = kk * N_NODES + j;
            float w = 0.0f;
            if (maskp[gi])
                w = s_wbf ? __bfloat162float(((const __hip_bfloat16*)Wp)[gi])
                          : ((const float*)Wp)[gi];
            const _Float16 hi = (_Float16)w;
            const _Float16 lo = (_Float16)(w - (float)hi);
            g_WT[OFF + n * KE + kk]           = hi;
            g_WT[OFF + 16 * KE + n * KE + kk] = lo;
        }
    }
    {   // triangular in-chunk weights, fp32
        const int l = tid >> 4, i = tid & 15;
        const int gi = (j0 + l) * N_NODES + (j0 + i);
        float w = 0.0f;
        if (l < i && maskp[gi])
            w = s_wbf ? __bfloat162float(((const __hip_bfloat16*)Wp)[gi])
                      : ((const float*)Wp)[gi];
        g_Wtri[(k - 1) * 256 + tid] = w;
    }
}

#define MFMA16(a, b, c) __builtin_amdgcn_mfma_f32_16x16x32_f16((a), (b), (c), 0, 0, 0)

// One 16-node chunk, everything compile-time-indexed.
// vf[q][t]: lane holds A[q*16 + (lane&15)][32t + (lane>>4)*8 .. +8] (fp16, *VSC)
template<int K>
__device__ __forceinline__ void do_chunk(
    const int lane, const long long sg,
    const void* __restrict__ eps, const bool ebf,
    half8 (&vf)[4][8],
    float* __restrict__ Zbuf, _Float16* __restrict__ stag,
    const short* __restrict__ xpos, const int* __restrict__ act_id,
    float* __restrict__ wsX,
    float* __restrict__ outX, float* __restrict__ outY, const int yi)
{
    constexpr int j0  = 16 * K;
    constexpr int KE  = KE_tab[K];
    constexpr int NST = KE / 32;
    constexpr int OFF = OFF_tab[K];

    const int mrow = lane & 15;
    const int quad = lane >> 4;

    // eps for this chunk (used only in the tail -> latency hidden under MFMAs)
    float ev[16];
    load16(eps, sg * (long long)N_COMP + (j0 - N_CAUSES), ebf, ev);

    const _Float16* __restrict__ bp = g_WT + OFF + mrow * KE + (quad << 3);

    f32x4 acc0 = {0.f,0.f,0.f,0.f}, acc1 = {0.f,0.f,0.f,0.f};
    f32x4 acc2 = {0.f,0.f,0.f,0.f}, acc3 = {0.f,0.f,0.f,0.f};

    #pragma unroll
    for (int t = 0; t < NST; ++t) {
        const half8 bh = *(const half8*)(bp + (t << 5));
        const half8 bl = *(const half8*)(bp + 16 * KE + (t << 5));
        acc0 = MFMA16(vf[0][t], bh, acc0);
        acc1 = MFMA16(vf[1][t], bh, acc1);
        acc2 = MFMA16(vf[2][t], bh, acc2);
        acc3 = MFMA16(vf[3][t], bh, acc3);
        acc0 = MFMA16(vf[0][t], bl, acc0);
        acc1 = MFMA16(vf[1][t], bl, acc1);
        acc2 = MFMA16(vf[2][t], bl, acc2);
        acc3 = MFMA16(vf[3][t], bl, acc3);
    }

    // C-layout (col=lane&15 = node, row=quad*4+reg = sample) -> Zbuf, unscaled
    {
        const int r0 = quad << 2;
        #pragma unroll
        for (int r = 0; r < 4; ++r) {
            Zbuf[(r0 + r)      * 21 + mrow] = acc0[r] * VSCI;
            Zbuf[(16 + r0 + r) * 21 + mrow] = acc1[r] * VSCI;
            Zbuf[(32 + r0 + r) * 21 + mrow] = acc2[r] * VSCI;
            Zbuf[(48 + r0 + r) * 21 + mrow] = acc3[r] * VSCI;
        }
    }
    __builtin_amdgcn_wave_barrier();   // single-wave block: LDS in-order

    // serial intra-chunk tail: sample = lane (fp32)
    float zz[16];
    #pragma unroll
    for (int i = 0; i < 16; ++i) zz[i] = Zbuf[lane * 21 + i];

    const float* __restrict__ tri = g_Wtri + (K - 1) * 256;
    float vn[16];
    half8 h0, h1;
    #pragma unroll
    for (int i = 0; i < 16; ++i) {
        float z = zz[i] + NOISE * ev[i];
        #pragma unroll
        for (int l = 0; l < i; ++l) z += tri[(l << 4) + i] * vn[l];
        const int a = act_id[j0 - N_CAUSES + i];   // wave-uniform -> s_load
        if (a == 1)      z = fast_tanh(z);
        else if (a == 2) z = fmaxf(z, 0.0f);
        else if (a == 3) z = fast_sigmoid(z);
        vn[i] = z;
        if (i < 8) h0[i] = (_Float16)(z * VSC);
        else       h1[i - 8] = (_Float16)(z * VSC);
        const int xp = xpos[j0 - N_CAUSES + i];    // wave-uniform value (LDS broadcast)
        if (xp >= 0) {
            if (wsX) wsX[(long long)xp * S_LEN + sg] = z;  // coalesced full-line
            else     outX[xp] = z;                         // fallback (scattered)
        }
        if (j0 + i == yi) outY[sg] = z;
    }

    // scatter new 16 node-values into the A-fragment register layout via staging
    *(half8*)(stag + lane * 24)     = h0;
    *(half8*)(stag + lane * 24 + 8) = h1;
    __builtin_amdgcn_wave_barrier();

    constexpr int TT = K >> 1;          // k-window of nodes j0..j0+15
    constexpr int HB = (K & 1) << 1;    // first owning lane-quad (j0%32)/8
    const int hq = lane >> 4;
    if (hq == HB || hq == HB + 1) {
        const int boff = (hq - HB) << 3;
        #pragma unroll
        for (int q = 0; q < 4; ++q)
            vf[q][TT] = *(const half8*)(stag + (q * 16 + (lane & 15)) * 24 + boff);
    }
    __builtin_amdgcn_wave_barrier();
}

__global__ __launch_bounds__(64, 2)
void scm_kernel(const void* __restrict__ causes,
                const void* __restrict__ eps,
                const int* __restrict__ act_id,
                const void* __restrict__ xidx_raw,
                const int* __restrict__ yidx_raw,
                float* __restrict__ out,
                float* __restrict__ wsX,
                long long ybase) {
    __shared__ __align__(16) float    Zbuf[64 * 21];   // 5376 B
    __shared__ __align__(16) _Float16 stag[64 * 24];   // 3072 B
    __shared__ short xpos[N_COMP];                     // 480 B

    const int lane = threadIdx.x;
    const long long sg = (long long)blockIdx.x * 64 + lane;

    for (int t = lane; t < N_COMP; t += 64) xpos[t] = -1;
    const unsigned long long* x64 = (const unsigned long long*)xidx_raw;
    const int*                x32 = (const int*)xidx_raw;
    const bool is64 = ((x64[0] >> 32) == 0ull);
    __builtin_amdgcn_wave_barrier();
    for (int f = lane; f < N_FEAT; f += 64) {
        const int ix = is64 ? (int)x64[f] : x32[f];
        xpos[ix - N_CAUSES] = (short)f;
    }
    __builtin_amdgcn_wave_barrier();
    const int yi  = yidx_raw[0];
    const bool cbf = sniff_is_bf16(causes);
    const bool ebf = sniff_is_bf16(eps);

    // vals in registers: vf[q][t], zero-initialized
    half8 vz;
    #pragma unroll
    for (int e = 0; e < 8; ++e) vz[e] = (_Float16)0.0f;
    half8 vf[4][8];
    #pragma unroll
    for (int q = 0; q < 4; ++q) {
        #pragma unroll
        for (int t = 0; t < 8; ++t) vf[q][t] = vz;
    }

    // causes (nodes 0..15) -> window 0, quads 0/1, via staging scatter
    {
        float cv[16];
        load16(causes, sg * (long long)N_CAUSES, cbf, cv);
        half8 c0, c1;
        #pragma unroll
        for (int i = 0; i < 8; ++i) {
            c0[i] = (_Float16)(cv[i] * VSC);
            c1[i] = (_Float16)(cv[8 + i] * VSC);
        }
        *(half8*)(stag + lane * 24)     = c0;
        *(half8*)(stag + lane * 24 + 8) = c1;
        __builtin_amdgcn_wave_barrier();
        const int hq = lane >> 4;
        if (hq < 2) {
            #pragma unroll
            for (int q = 0; q < 4; ++q)
                vf[q][0] = *(const half8*)(stag + (q * 16 + (lane & 15)) * 24 + (hq << 3));
        }
        __builtin_amdgcn_wave_barrier();
    }

    float* outX = out + sg * N_FEAT;
    float* outY = out + ybase;

    do_chunk< 1>(lane, sg, eps, ebf, vf, Zbuf, stag, xpos, act_id, wsX, outX, outY, yi);
    do_chunk< 2>(lane, sg, eps, ebf, vf, Zbuf, stag, xpos, act_id, wsX, outX, outY, yi);
    do_chunk< 3>(lane, sg, eps, ebf, vf, Zbuf, stag, xpos, act_id, wsX, outX, outY, yi);
    do_chunk< 4>(lane, sg, eps, ebf, vf, Zbuf, stag, xpos, act_id, wsX, outX, outY, yi);
    do_chunk< 5>(lane, sg, eps, ebf, vf, Zbuf, stag, xpos, act_id, wsX, outX, outY, yi);
    do_chunk< 6>(lane, sg, eps, ebf, vf, Zbuf, stag, xpos, act_id, wsX, outX, outY, yi);
    do_chunk< 7>(lane, sg, eps, ebf, vf, Zbuf, stag, xpos, act_id, wsX, outX, outY, yi);
    do_chunk< 8>(lane, sg, eps, ebf, vf, Zbuf, stag, xpos, act_id, wsX, outX, outY, yi);
    do_chunk< 9>(lane, sg, eps, ebf, vf, Zbuf, stag, xpos, act_id, wsX, outX, outY, yi);
    do_chunk<10>(lane, sg, eps, ebf, vf, Zbuf, stag, xpos, act_id, wsX, outX, outY, yi);
    do_chunk<11>(lane, sg, eps, ebf, vf, Zbuf, stag, xpos, act_id, wsX, outX, outY, yi);
    do_chunk<12>(lane, sg, eps, ebf, vf, Zbuf, stag, xpos, act_id, wsX, outX, outY, yi);
    do_chunk<13>(lane, sg, eps, ebf, vf, Zbuf, stag, xpos, act_id, wsX, outX, outY, yi);
    do_chunk<14>(lane, sg, eps, ebf, vf, Zbuf, stag, xpos, act_id, wsX, outX, outY, yi);
    do_chunk<15>(lane, sg, eps, ebf, vf, Zbuf, stag, xpos, act_id, wsX, outX, outY, yi);
}

// ---------- transpose: ws[100][S] -> out[S][100] ----------
__global__ __launch_bounds__(256)
void xpose_kernel(const float* __restrict__ ws, float* __restrict__ out) {
    __shared__ float tile[64 * 100];   // 25.6 KB, flat == out layout for this block
    const int tid = threadIdx.x;
    const long long s0 = (long long)blockIdx.x * 64;
    const int f = tid >> 6;        // base feature (0..3)
    const int s = tid & 63;
    #pragma unroll
    for (int g = 0; g < 25; ++g) {
        const int ff = f + g * 4;
        tile[s * 100 + ff] = ws[(long long)ff * S_LEN + s0 + s];  // coalesced read
    }
    __syncthreads();
    float4* o4 = (float4*)(out + s0 * N_FEAT);    // contiguous 25.6 KB span
    const float4* t4 = (const float4*)tile;
    #pragma unroll
    for (int g = 0; g < 7; ++g) {
        const int idx = g * 256 + tid;
        if (idx < 1600) o4[idx] = t4[idx];        // coalesced dwordx4 write
    }
}

extern "C" void kernel_launch(void* const* d_in, const int* in_sizes, int n_in,
                              void* d_out, int out_size, void* d_ws, size_t ws_size,
                              hipStream_t stream) {
    // resolve inputs by element count (permutation-proof); fall back to dict order
    int ic = 0, iw = 1, ie = 2, im = 3, ia = 4, ix = 5, iy = 6;
    int c = -1, e = -1, a = -1, x = -1, y = -1, m1 = -1, m2 = -1;
    for (int i = 0; i < n_in; ++i) {
        switch (in_sizes[i]) {
            case S_LEN * N_CAUSES:   c = i; break;
            case S_LEN * N_COMP:     e = i; break;
            case N_COMP:             a = i; break;
            case N_FEAT:             x = i; break;
            case 1:                  y = i; break;
            case N_NODES * N_NODES:  (m1 < 0 ? m1 : m2) = i; break;
        }
    }
    if (c >= 0 && e >= 0 && a >= 0 && x >= 0 && y >= 0 && m1 >= 0 && m2 >= 0) {
        ic = c; ie = e; ia = a; ix = x; iy = y; iw = m1; im = m2;
    }

    const void* causes = d_in[ic];
    const void* TA     = d_in[iw];   // one of {W, mask} — device disambiguates
    const void* TB     = d_in[im];
    const void* eps    = d_in[ie];
    const int*  act_id = (const int*)d_in[ia];
    const void* xidx   = d_in[ix];
    const int*  yidx   = (const int*)d_in[iy];
    float*      out    = (float*)d_out;
    const long long ybase = (long long)out_size - S_LEN;

    const bool usews = ws_size >= (size_t)N_FEAT * S_LEN * sizeof(float);
    float* wsX = usews ? (float*)d_ws : nullptr;

    prep_kernel<<<15, 256, 0, stream>>>(TA, TB);
    scm_kernel<<<S_LEN / 64, 64, 0, stream>>>(causes, eps, act_id, xidx, yidx,
                                              out, wsX, ybase);
    if (usews)
        xpose_kernel<<<S_LEN / 64, 256, 0, stream>>>(wsX, out);
}

// Round 3
// 353.426 us; speedup vs baseline: 1.2605x; 1.0073x over previous
//
#include <hip/hip_runtime.h>
#include <hip/hip_bf16.h>
#include <hip/hip_fp16.h>

// MLPSCM round 12: 4 waves/SIMD + ILP tail.
// R11 counters: scm 172us, MfmaUtil 4.2%, VALUBusy 13%, Occupancy 23%
// (doubly capped: grid 8 waves/CU AND vgpr 104+~144agpr -> 2 waves/SIMD).
// Changes:
//  - 32 samples/wave, 4096 blocks: vf[2][8] (64 regs), hi/lo split accs
//    (4 indep MFMA chains), __launch_bounds__(64,4) -> 128-reg budget,
//    16 waves/CU. Per-wave B-loads unchanged; L2 B-traffic 2x (~3.4TB/s,
//    far under 34.5 TB/s ceiling).
//  - scatter-form triangular tail (bit-identical sum order): vn[i]=act(zz[i])
//    then zz[j] += tri[i][j]*vn[i] for j>i — updates independent, critical
//    path 16*(act+FMA) instead of 16*act + 120 serial FMAs; vn array gone.
//  - tail/eps/causes under lane<32 (uniform branch).
//  - everything else per R11 (ws feature-major X + xpose, wave_barrier,
//    fast activations, hi/lo fp16 W planes).

typedef _Float16 half8 __attribute__((ext_vector_type(8)));
typedef float    f32x4 __attribute__((ext_vector_type(4)));

constexpr int S_LEN    = 131072;
constexpr int N_NODES  = 256;
constexpr int N_CAUSES = 16;
constexpr int N_COMP   = 240;
constexpr int N_FEAT   = 100;
constexpr float NOISE  = 0.01f;
constexpr float VSC    = 0.0625f;   // vals store scale 1/16
constexpr float VSCI   = 16.0f;

// K_eff per chunk (K=16k+16 rounded up to 32) and hi/lo-plane pack offsets
constexpr int KE_tab[16]  = {0,32,64,64,96,96,128,128,160,160,192,192,224,224,256,256};
constexpr int OFF_tab[16] = {0,0,1024,3072,5120,8192,11264,15360,19456,24576,29696,
                             35840,41984,49152,56320,64512};

__constant__ int c_KE[16]  = {0,32,64,64,96,96,128,128,160,160,192,192,224,224,256,256};
__constant__ int c_OFF[16] = {0,0,1024,3072,5120,8192,11264,15360,19456,24576,29696,
                              35840,41984,49152,56320,64512};

__device__ _Float16 g_WT[72704];      // per chunk: [hi|lo] planes of [16 cols][KE] W^T
__device__ float    g_Wtri[15 * 256]; // per chunk: [l][i] in-chunk triangular W (fp32)

// ---------- content sniffers ----------
__device__ __forceinline__ bool sniff_binary64(const void* p) {
    const unsigned* u = (const unsigned*)p;
    bool ok = true;
    for (int i = 0; i < 64; ++i) ok = ok && (u[i] <= 1u);
    return ok;
}
__device__ __forceinline__ bool sniff_is_bf16(const void* p) {
    const unsigned* u = (const unsigned*)p;
    bool ok = true;
    for (int i = 0; i < 16; ++i) {
        unsigned e = ((u[i] << 16) >> 23) & 0xffu;
        ok = ok && (e >= 100u) && (e <= 132u);
    }
    return ok;
}
__device__ __forceinline__ float bflo(unsigned u) { return __uint_as_float(u << 16); }
__device__ __forceinline__ float bfhi(unsigned u) { return __uint_as_float(u & 0xffff0000u); }

__device__ __forceinline__ void load16(const void* base, long long off, bool isbf, float* o) {
    if (isbf) {
        const uint4* p = (const uint4*)((const unsigned short*)base + off);
        uint4 a = p[0], b = p[1];
        o[0]=bflo(a.x); o[1]=bfhi(a.x); o[2]=bflo(a.y); o[3]=bfhi(a.y);
        o[4]=bflo(a.z); o[5]=bfhi(a.z); o[6]=bflo(a.w); o[7]=bfhi(a.w);
        o[8]=bflo(b.x); o[9]=bfhi(b.x); o[10]=bflo(b.y); o[11]=bfhi(b.y);
        o[12]=bflo(b.z); o[13]=bfhi(b.z); o[14]=bflo(b.w); o[15]=bfhi(b.w);
    } else {
        const float4* p = (const float4*)((const float*)base + off);
        float4 x0=p[0], x1=p[1], x2=p[2], x3=p[3];
        o[0]=x0.x; o[1]=x0.y; o[2]=x0.z; o[3]=x0.w;
        o[4]=x1.x; o[5]=x1.y; o[6]=x1.z; o[7]=x1.w;
        o[8]=x2.x; o[9]=x2.y; o[10]=x2.z; o[11]=x2.w;
        o[12]=x3.x; o[13]=x3.y; o[14]=x3.z; o[15]=x3.w;
    }
}

// ---------- fast activations (raw HW transcendentals; err ~1e-7 rel) ----------
__device__ __forceinline__ float hw_exp2(float x) {
    float r; asm("v_exp_f32 %0, %1" : "=v"(r) : "v"(x)); return r;
}
__device__ __forceinline__ float hw_rcp(float x) {
    float r; asm("v_rcp_f32 %0, %1" : "=v"(r) : "v"(x)); return r;
}
__device__ __forceinline__ float fast_tanh(float x) {
    float t = hw_exp2(x * 2.88539008177792681f);
    return 1.0f - 2.0f * hw_rcp(t + 1.0f);
}
__device__ __forceinline__ float fast_sigmoid(float x) {
    return hw_rcp(1.0f + hw_exp2(x * -1.44269504088896341f));
}

// ---------- prep: pack W^T hi/lo fp16 per chunk + fp32 triangular ----------
__global__ void prep_kernel(const void* __restrict__ A, const void* __restrict__ B) {
    __shared__ int s_mA, s_wbf;
    if (threadIdx.x == 0) {
        s_mA  = sniff_binary64(A) ? 1 : 0;
        s_wbf = sniff_is_bf16(s_mA ? B : A) ? 1 : 0;
    }
    __syncthreads();
    const int*  maskp = (const int*)(s_mA ? A : B);
    const void* Wp    = s_mA ? B : A;
    const int k = blockIdx.x + 1, j0 = 16 * k, KE = c_KE[k], OFF = c_OFF[k];
    const int tid = threadIdx.x;

    for (int n = 0; n < 16; ++n) {
        const int j = j0 + n;
        for (int kk = tid; kk < KE; kk += 256) {
            const int gi = kk * N_NODES + j;
            float w = 0.0f;
            if (maskp[gi])
                w = s_wbf ? __bfloat162float(((const __hip_bfloat16*)Wp)[gi])
                          : ((const float*)Wp)[gi];
            const _Float16 hi = (_Float16)w;
            const _Float16 lo = (_Float16)(w - (float)hi);
            g_WT[OFF + n * KE + kk]           = hi;
            g_WT[OFF + 16 * KE + n * KE + kk] = lo;
        }
    }
    {   // triangular in-chunk weights, fp32
        const int l = tid >> 4, i = tid & 15;
        const int gi = (j0 + l) * N_NODES + (j0 + i);
        float w = 0.0f;
        if (l < i && maskp[gi])
            w = s_wbf ? __bfloat162float(((const __hip_bfloat16*)Wp)[gi])
                      : ((const float*)Wp)[gi];
        g_Wtri[(k - 1) * 256 + tid] = w;
    }
}

#define MFMA16(a, b, c) __builtin_amdgcn_mfma_f32_16x16x32_f16((a), (b), (c), 0, 0, 0)

// One 16-node chunk, everything compile-time-indexed. 32 samples/wave.
// vf[q][t]: lane holds A[q*16 + (lane&15)][32t + (lane>>4)*8 .. +8] (fp16, *VSC)
template<int K>
__device__ __forceinline__ void do_chunk(
    const int lane, const long long sg,
    const void* __restrict__ eps, const bool ebf,
    half8 (&vf)[2][8],
    float* __restrict__ Zbuf, _Float16* __restrict__ stag,
    const short* __restrict__ xpos, const int* __restrict__ act_id,
    float* __restrict__ wsX,
    float* __restrict__ outX, float* __restrict__ outY, const int yi)
{
    constexpr int j0  = 16 * K;
    constexpr int KE  = KE_tab[K];
    constexpr int NST = KE / 32;
    constexpr int OFF = OFF_tab[K];

    const int mrow = lane & 15;
    const int quad = lane >> 4;

    // eps for this chunk (consumed in tail -> latency hidden under MFMAs)
    float ev[16];
    if (lane < 32)
        load16(eps, sg * (long long)N_COMP + (j0 - N_CAUSES), ebf, ev);

    const _Float16* __restrict__ bp = g_WT + OFF + mrow * KE + (quad << 3);

    f32x4 acc0h = {0.f,0.f,0.f,0.f}, acc0l = {0.f,0.f,0.f,0.f};
    f32x4 acc1h = {0.f,0.f,0.f,0.f}, acc1l = {0.f,0.f,0.f,0.f};

    #pragma unroll
    for (int t = 0; t < NST; ++t) {
        const half8 bh = *(const half8*)(bp + (t << 5));
        const half8 bl = *(const half8*)(bp + 16 * KE + (t << 5));
        acc0h = MFMA16(vf[0][t], bh, acc0h);   // 4 independent chains
        acc1h = MFMA16(vf[1][t], bh, acc1h);
        acc0l = MFMA16(vf[0][t], bl, acc0l);
        acc1l = MFMA16(vf[1][t], bl, acc1l);
    }

    // C-layout (col=lane&15 = node, row=quad*4+reg = sample) -> Zbuf, unscaled
    {
        const int r0 = quad << 2;
        #pragma unroll
        for (int r = 0; r < 4; ++r) {
            Zbuf[(r0 + r)      * 21 + mrow] = (acc0h[r] + acc0l[r]) * VSCI;
            Zbuf[(16 + r0 + r) * 21 + mrow] = (acc1h[r] + acc1l[r]) * VSCI;
        }
    }
    __builtin_amdgcn_wave_barrier();   // single-wave block: LDS in-order

    // intra-chunk tail, scatter form: sample = lane (lanes 0..31)
    if (lane < 32) {
        float zz[16];
        #pragma unroll
        for (int i = 0; i < 16; ++i)
            zz[i] = Zbuf[lane * 21 + i] + NOISE * ev[i];

        const float* __restrict__ tri = g_Wtri + (K - 1) * 256;
        half8 h0, h1;
        #pragma unroll
        for (int i = 0; i < 16; ++i) {
            float z = zz[i];
            const int a = act_id[j0 - N_CAUSES + i];   // wave-uniform -> s_load
            if (a == 1)      z = fast_tanh(z);
            else if (a == 2) z = fmaxf(z, 0.0f);
            else if (a == 3) z = fast_sigmoid(z);
            if (i < 8) h0[i] = (_Float16)(z * VSC);
            else       h1[i - 8] = (_Float16)(z * VSC);
            const int xp = xpos[j0 - N_CAUSES + i];    // wave-uniform (LDS broadcast)
            if (xp >= 0) {
                if (wsX) wsX[(long long)xp * S_LEN + sg] = z;  // coalesced
                else     outX[xp] = z;                         // fallback
            }
            if (j0 + i == yi) outY[sg] = z;
            // independent forward updates (same summation order as gather form)
            #pragma unroll
            for (int j = i + 1; j < 16; ++j)
                zz[j] += tri[(i << 4) + j] * z;
        }
        *(half8*)(stag + lane * 24)     = h0;
        *(half8*)(stag + lane * 24 + 8) = h1;
    }
    __builtin_amdgcn_wave_barrier();

    // scatter new 16 node-values into the A-fragment register layout
    constexpr int TT = K >> 1;          // k-window of nodes j0..j0+15
    constexpr int HB = (K & 1) << 1;    // first owning lane-quad (j0%32)/8
    const int hq = lane >> 4;
    if (hq == HB || hq == HB + 1) {
        const int boff = (hq - HB) << 3;
        #pragma unroll
        for (int q = 0; q < 2; ++q)
            vf[q][TT] = *(const half8*)(stag + (q * 16 + (lane & 15)) * 24 + boff);
    }
    __builtin_amdgcn_wave_barrier();
}

__global__ __launch_bounds__(64, 4)
void scm_kernel(const void* __restrict__ causes,
                const void* __restrict__ eps,
                const int* __restrict__ act_id,
                const void* __restrict__ xidx_raw,
                const int* __restrict__ yidx_raw,
                float* __restrict__ out,
                float* __restrict__ wsX,
                long long ybase) {
    __shared__ __align__(16) float    Zbuf[32 * 21];   // 2688 B
    __shared__ __align__(16) _Float16 stag[32 * 24];   // 1536 B
    __shared__ short xpos[N_COMP];                     // 480 B

    const int lane = threadIdx.x;
    const long long sg = (long long)blockIdx.x * 32 + lane;  // valid for lane<32

    for (int t = lane; t < N_COMP; t += 64) xpos[t] = -1;
    const unsigned long long* x64 = (const unsigned long long*)xidx_raw;
    const int*                x32 = (const int*)xidx_raw;
    const bool is64 = ((x64[0] >> 32) == 0ull);
    __builtin_amdgcn_wave_barrier();
    for (int f = lane; f < N_FEAT; f += 64) {
        const int ix = is64 ? (int)x64[f] : x32[f];
        xpos[ix - N_CAUSES] = (short)f;
    }
    __builtin_amdgcn_wave_barrier();
    const int yi  = yidx_raw[0];
    const bool cbf = sniff_is_bf16(causes);
    const bool ebf = sniff_is_bf16(eps);

    // vals in registers: vf[q][t], zero-initialized
    half8 vz;
    #pragma unroll
    for (int e = 0; e < 8; ++e) vz[e] = (_Float16)0.0f;
    half8 vf[2][8];
    #pragma unroll
    for (int q = 0; q < 2; ++q) {
        #pragma unroll
        for (int t = 0; t < 8; ++t) vf[q][t] = vz;
    }

    // causes (nodes 0..15) -> window 0, quads 0/1, via staging scatter
    if (lane < 32) {
        float cv[16];
        load16(causes, sg * (long long)N_CAUSES, cbf, cv);
        half8 c0, c1;
        #pragma unroll
        for (int i = 0; i < 8; ++i) {
            c0[i] = (_Float16)(cv[i] * VSC);
            c1[i] = (_Float16)(cv[8 + i] * VSC);
        }
        *(half8*)(stag + lane * 24)     = c0;
        *(half8*)(stag + lane * 24 + 8) = c1;
    }
    __builtin_amdgcn_wave_barrier();
    {
        const int hq = lane >> 4;
        if (hq < 2) {
            #pragma unroll
            for (int q = 0; q < 2; ++q)
                vf[q][0] = *(const half8*)(stag + (q * 16 + (lane & 15)) * 24 + (hq << 3));
        }
    }
    __builtin_amdgcn_wave_barrier();

    float* outX = out + sg * N_FEAT;
    float* outY = out + ybase;

    do_chunk< 1>(lane, sg, eps, ebf, vf, Zbuf, stag, xpos, act_id, wsX, outX, outY, yi);
    do_chunk< 2>(lane, sg, eps, ebf, vf, Zbuf, stag, xpos, act_id, wsX, outX, outY, yi);
    do_chunk< 3>(lane, sg, eps, ebf, vf, Zbuf, stag, xpos, act_id, wsX, outX, outY, yi);
    do_chunk< 4>(lane, sg, eps, ebf, vf, Zbuf, stag, xpos, act_id, wsX, outX, outY, yi);
    do_chunk< 5>(lane, sg, eps, ebf, vf, Zbuf, stag, xpos, act_id, wsX, outX, outY, yi);
    do_chunk< 6>(lane, sg, eps, ebf, vf, Zbuf, stag, xpos, act_id, wsX, outX, outY, yi);
    do_chunk< 7>(lane, sg, eps, ebf, vf, Zbuf, stag, xpos, act_id, wsX, outX, outY, yi);
    do_chunk< 8>(lane, sg, eps, ebf, vf, Zbuf, stag, xpos, act_id, wsX, outX, outY, yi);
    do_chunk< 9>(lane, sg, eps, ebf, vf, Zbuf, stag, xpos, act_id, wsX, outX, outY, yi);
    do_chunk<10>(lane, sg, eps, ebf, vf, Zbuf, stag, xpos, act_id, wsX, outX, outY, yi);
    do_chunk<11>(lane, sg, eps, ebf, vf, Zbuf, stag, xpos, act_id, wsX, outX, outY, yi);
    do_chunk<12>(lane, sg, eps, ebf, vf, Zbuf, stag, xpos, act_id, wsX, outX, outY, yi);
    do_chunk<13>(lane, sg, eps, ebf, vf, Zbuf, stag, xpos, act_id, wsX, outX, outY, yi);
    do_chunk<14>(lane, sg, eps, ebf, vf, Zbuf, stag, xpos, act_id, wsX, outX, outY, yi);
    do_chunk<15>(lane, sg, eps, ebf, vf, Zbuf, stag, xpos, act_id, wsX, outX, outY, yi);
}

// ---------- transpose: ws[100][S] -> out[S][100] ----------
__global__ __launch_bounds__(256)
void xpose_kernel(const float* __restrict__ ws, float* __restrict__ out) {
    __shared__ float tile[64 * 100];   // 25.6 KB, flat == out layout for this block
    const int tid = threadIdx.x;
    const long long s0 = (long long)blockIdx.x * 64;
    const int f = tid >> 6;        // base feature (0..3)
    const int s = tid & 63;
    #pragma unroll
    for (int g = 0; g < 25; ++g) {
        const int ff = f + g * 4;
        tile[s * 100 + ff] = ws[(long long)ff * S_LEN + s0 + s];  // coalesced read
    }
    __syncthreads();
    float4* o4 = (float4*)(out + s0 * N_FEAT);    // contiguous 25.6 KB span
    const float4* t4 = (const float4*)tile;
    #pragma unroll
    for (int g = 0; g < 7; ++g) {
        const int idx = g * 256 + tid;
        if (idx < 1600) o4[idx] = t4[idx];        // coalesced dwordx4 write
    }
}

extern "C" void kernel_launch(void* const* d_in, const int* in_sizes, int n_in,
                              void* d_out, int out_size, void* d_ws, size_t ws_size,
                              hipStream_t stream) {
    // resolve inputs by element count (permutation-proof); fall back to dict order
    int ic = 0, iw = 1, ie = 2, im = 3, ia = 4, ix = 5, iy = 6;
    int c = -1, e = -1, a = -1, x = -1, y = -1, m1 = -1, m2 = -1;
    for (int i = 0; i < n_in; ++i) {
        switch (in_sizes[i]) {
            case S_LEN * N_CAUSES:   c = i; break;
            case S_LEN * N_COMP:     e = i; break;
            case N_COMP:             a = i; break;
            case N_FEAT:             x = i; break;
            case 1:                  y = i; break;
            case N_NODES * N_NODES:  (m1 < 0 ? m1 : m2) = i; break;
        }
    }
    if (c >= 0 && e >= 0 && a >= 0 && x >= 0 && y >= 0 && m1 >= 0 && m2 >= 0) {
        ic = c; ie = e; ia = a; ix = x; iy = y; iw = m1; im = m2;
    }

    const void* causes = d_in[ic];
    const void* TA     = d_in[iw];   // one of {W, mask} — device disambiguates
    const void* TB     = d_in[im];
    const void* eps    = d_in[ie];
    const int*  act_id = (const int*)d_in[ia];
    const void* xidx   = d_in[ix];
    const int*  yidx   = (const int*)d_in[iy];
    float*      out    = (float*)d_out;
    const long long ybase = (long long)out_size - S_LEN;

    const bool usews = ws_size >= (size_t)N_FEAT * S_LEN * sizeof(float);
    float* wsX = usews ? (float*)d_ws : nullptr;

    prep_kernel<<<15, 256, 0, stream>>>(TA, TB);
    scm_kernel<<<S_LEN / 32, 64, 0, stream>>>(causes, eps, act_id, xidx, yidx,
                                              out, wsX, ybase);
    if (usews)
        xpose_kernel<<<S_LEN / 64, 256, 0, stream>>>(wsX, out);
}